// Round 2
// baseline (1248.171 us; speedup 1.0000x reference)
//
#include <hip/hip_runtime.h>
#include <hip/hip_bf16.h>
#include <stdint.h>

#define B_SZ 16384
#define H_SZ 1024
#define OUT_SZ 128

typedef __attribute__((ext_vector_type(4))) float f32x4;
typedef __attribute__((ext_vector_type(8))) short s16x8;
typedef unsigned short u16;
typedef unsigned int u32;

__device__ __forceinline__ u16 f2bf(float f) {
  union { float f; u32 u; } v; v.f = f;
  u32 u = v.u;
  return (u16)((u + 0x7FFFu + ((u >> 16) & 1u)) >> 16);
}
__device__ __forceinline__ float bf2f(u16 h) {
  union { u32 u; float f; } v; v.u = ((u32)h) << 16; return v.f;
}
__device__ __forceinline__ u32 pk2(float a, float b) {
  return (u32)f2bf(a) | ((u32)f2bf(b) << 16);
}

__device__ __forceinline__ void gl_lds16(const void* g, void* l) {
  __builtin_amdgcn_global_load_lds(
      (const __attribute__((address_space(1))) u32*)g,
      (__attribute__((address_space(3))) u32*)l, 16, 0, 0);
}

// ---------------------------------------------------------------------------
// NT GEMM: C[m,n] = sum_k A[m,k] * B[n,k], bf16 in, fp32 MFMA accum.
// BM=BN=128, BK=32, 256 threads (4 waves, 64x64 each via 4x4 mfma 16x16x32).
// SPLIT=1 (requires K==1024): 3 passes -> Ahi*Bhi + Ahi*Blo + Alo*Bhi,
//   i.e. split-bf16 product accurate to ~2^-17 relative.
// MODE 0: epilogue stores hi/lo bf16 split of C -> ep_b/ep_b2 (AT prep)
// MODE 1: A = Z (4 stacked [B,H]; row m -> token m&3, batch m>>2);
//         epilogue: partial logits (R[t,n]+ak[n])*z_fp32[s,n] atomicAdd ep_f
// MODE 2: v = acc + 4*ep_v[n]; fp32 -> ep_f, bf16 hi/lo -> ep_b/ep_b2
// MODE 3: ep_f[m*N+n] = acc + ep_v[n]   (fc logits)
// ---------------------------------------------------------------------------
template<int MODE, int SPLIT>
__global__ __launch_bounds__(256, 2) void gemm_nt(
    const u16* __restrict__ Ahi, const u16* __restrict__ Alo,
    const u16* __restrict__ Bhi, const u16* __restrict__ Blo,
    int N, int K,
    float* __restrict__ ep_f, u16* __restrict__ ep_b, u16* __restrict__ ep_b2,
    const float* __restrict__ ep_v,
    const float* zf0, const float* zf1, const float* zf2, const float* zf3)
{
  constexpr int BM = 128, BN = 128, BK = 32;
  __shared__ __align__(16) u16 sA[BM * BK];
  __shared__ __align__(16) u16 sB[BN * BK];
  const int tid  = threadIdx.x;
  const int wave = tid >> 6;
  const int lane = tid & 63;
  const int qd   = lane >> 4;
  const int c16  = lane & 15;
  const int bn0  = blockIdx.x * BN;
  const int bm0  = blockIdx.y * BM;
  const int wm   = (wave >> 1) * 64;
  const int wn   = (wave & 1) * 64;
  const size_t FBS = (size_t)B_SZ * H_SZ;

  f32x4 acc[4][4];
#pragma unroll
  for (int i = 0; i < 4; ++i)
#pragma unroll
    for (int j = 0; j < 4; ++j)
      acc[i][j] = (f32x4){0.f, 0.f, 0.f, 0.f};

  const int KT = SPLIT ? 3 * K : K;
  for (int k0t = 0; k0t < KT; k0t += BK) {
    int seg, k0;
    if (SPLIT) { seg = k0t >> 10; k0 = k0t & 1023; }  // K==1024 required
    else       { seg = 0;         k0 = k0t; }
    const u16* Asrc = (SPLIT && seg == 2) ? Alo : Ahi;
    const u16* Bsrc = (SPLIT && seg == 1) ? Blo : Bhi;
    // ---- stage: 512 x 16B chunks per tile; LDS slot s holds global chunk
    // c = (s&3) ^ ((row>>1)&3) of row s>>2 (XOR swizzle).
#pragma unroll
    for (int i = 0; i < 2; ++i) {
      int slot = tid + i * 256;
      int r = slot >> 2, pp = slot & 3;
      int cc = pp ^ ((r >> 1) & 3);
      {
        int gm = bm0 + r;
        const u16* gp;
        if (MODE == 1)
          gp = Asrc + (size_t)(gm & 3) * FBS + (size_t)(gm >> 2) * H_SZ + (k0 + cc * 8);
        else
          gp = Asrc + (size_t)gm * K + (k0 + cc * 8);
        gl_lds16(gp, &sA[(size_t)(slot & ~63) * 8]);
      }
      {
        int gn = bn0 + r;
        const u16* gp = Bsrc + (size_t)gn * K + (k0 + cc * 8);
        gl_lds16(gp, &sB[(size_t)(slot & ~63) * 8]);
      }
    }
    __syncthreads();
    s16x8 af[4], bfr[4];
#pragma unroll
    for (int im = 0; im < 4; ++im) {
      int m = wm + im * 16 + c16;
      int slot = m * 4 + (qd ^ ((m >> 1) & 3));
      af[im] = *(const s16x8*)&sA[slot * 8];
    }
#pragma unroll
    for (int in = 0; in < 4; ++in) {
      int n = wn + in * 16 + c16;
      int slot = n * 4 + (qd ^ ((n >> 1) & 3));
      bfr[in] = *(const s16x8*)&sB[slot * 8];
    }
#pragma unroll
    for (int im = 0; im < 4; ++im)
#pragma unroll
      for (int in = 0; in < 4; ++in)
        acc[im][in] = __builtin_amdgcn_mfma_f32_16x16x32_bf16(af[im], bfr[in], acc[im][in], 0, 0, 0);
    __syncthreads();
  }

  if constexpr (MODE == 0) {
#pragma unroll
    for (int im = 0; im < 4; ++im)
#pragma unroll
      for (int in = 0; in < 4; ++in) {
        int n = bn0 + wn + in * 16 + c16;
#pragma unroll
        for (int r = 0; r < 4; ++r) {
          int m = bm0 + wm + im * 16 + qd * 4 + r;
          float v = acc[im][in][r];
          u16 h = f2bf(v);
          ep_b[(size_t)m * N + n]  = h;
          ep_b2[(size_t)m * N + n] = f2bf(v - bf2f(h));
        }
      }
  } else if constexpr (MODE == 1) {
    // acc row m = bm0+wm+im*16+qd*4+r -> batch b = m>>2, token t = r.
    // partial logit[b,t,s] over this block's 64 cols per wave:
    //   sum_n (R[t,n] + ak[n]) * z_fp32[s][b,n]
    const float* zf[4] = {zf0, zf1, zf2, zf3};
#pragma unroll
    for (int im = 0; im < 4; ++im) {
      int mrow = bm0 + wm + im * 16 + qd * 4;
      size_t b = (size_t)(mrow >> 2);
      float p[4][4];
#pragma unroll
      for (int r = 0; r < 4; ++r)
#pragma unroll
        for (int s = 0; s < 4; ++s) p[r][s] = 0.f;
#pragma unroll
      for (int in = 0; in < 4; ++in) {
        int n = bn0 + wn + in * 16 + c16;
        float akv = ep_v[n];
        float rv[4];
#pragma unroll
        for (int r = 0; r < 4; ++r) rv[r] = acc[im][in][r] + akv;
#pragma unroll
        for (int s = 0; s < 4; ++s) {
          float zv = zf[s][b * H_SZ + n];
#pragma unroll
          for (int r = 0; r < 4; ++r) p[r][s] += rv[r] * zv;
        }
      }
#pragma unroll
      for (int r = 0; r < 4; ++r)
#pragma unroll
        for (int s = 0; s < 4; ++s) {
          float v = p[r][s];
          v += __shfl_xor(v, 1);
          v += __shfl_xor(v, 2);
          v += __shfl_xor(v, 4);
          v += __shfl_xor(v, 8);
          if (c16 == 0) atomicAdd(&ep_f[b * 16 + r * 4 + s], v);
        }
    }
  } else if constexpr (MODE == 2) {
#pragma unroll
    for (int im = 0; im < 4; ++im)
#pragma unroll
      for (int in = 0; in < 4; ++in) {
        int n = bn0 + wn + in * 16 + c16;
        float bvv = 4.0f * ep_v[n];
#pragma unroll
        for (int r = 0; r < 4; ++r) {
          int m = bm0 + wm + im * 16 + qd * 4 + r;
          float v = acc[im][in][r] + bvv;
          ep_f[(size_t)m * H_SZ + n] = v;
          u16 h = f2bf(v);
          ep_b[(size_t)m * H_SZ + n]  = h;
          ep_b2[(size_t)m * H_SZ + n] = f2bf(v - bf2f(h));
        }
      }
  } else {
#pragma unroll
    for (int im = 0; im < 4; ++im)
#pragma unroll
      for (int in = 0; in < 4; ++in) {
        int n = bn0 + wn + in * 16 + c16;
        float bc = ep_v[n];
#pragma unroll
        for (int r = 0; r < 4; ++r) {
          int m = bm0 + wm + im * 16 + qd * 4 + r;
          ep_f[(size_t)m * N + n] = acc[im][in][r] + bc;
        }
      }
  }
}

// ---------------------------------------------------------------------------
// prep_weights: [0,1024) Wq hi/lo split; [1024,2048) Wk hi/lo split;
// [2048,3072) WvT bf16 transpose; [3072,3200) WfcT transpose + hi/lo split;
// [3200,3456) ak[h] = sum_i Wk[h,i]*bq[i]  (fp32)
// ---------------------------------------------------------------------------
__global__ __launch_bounds__(256) void prep_weights(
    const float* __restrict__ Wq, const float* __restrict__ Wk,
    const float* __restrict__ Wv, const float* __restrict__ Wfc,
    const float* __restrict__ bq,
    u16* __restrict__ Wqhi, u16* __restrict__ Wqlo,
    u16* __restrict__ Wkhi, u16* __restrict__ Wklo,
    u16* __restrict__ WvT,
    u16* __restrict__ WfcThi, u16* __restrict__ WfcTlo,
    float* __restrict__ ak)
{
  __shared__ float t[32][33];
  int blk = blockIdx.x, tid = threadIdx.x;
  if (blk < 2048) {
    const float* src = (blk < 1024) ? Wq : Wk;
    u16* dh = (blk < 1024) ? Wqhi : Wkhi;
    u16* dl = (blk < 1024) ? Wqlo : Wklo;
    size_t i0 = (size_t)(blk & 1023) * 1024 + tid * 4;
    float4 v = *(const float4*)(src + i0);
    u16 h0 = f2bf(v.x), h1 = f2bf(v.y), h2 = f2bf(v.z), h3 = f2bf(v.w);
    *(uint2*)(dh + i0) = make_uint2((u32)h0 | ((u32)h1 << 16), (u32)h2 | ((u32)h3 << 16));
    *(uint2*)(dl + i0) = make_uint2(
        (u32)f2bf(v.x - bf2f(h0)) | ((u32)f2bf(v.y - bf2f(h1)) << 16),
        (u32)f2bf(v.z - bf2f(h2)) | ((u32)f2bf(v.w - bf2f(h3)) << 16));
  } else if (blk < 3200) {
    int lx = tid & 31, ly = tid >> 5;
    if (blk < 3072) {
      int ti = blk - 2048;
      int tx = ti & 31, ty = ti >> 5;
#pragma unroll
      for (int k = 0; k < 4; ++k)
        t[ly + 8 * k][lx] = Wv[(size_t)(ty * 32 + ly + 8 * k) * 1024 + tx * 32 + lx];
      __syncthreads();
#pragma unroll
      for (int k = 0; k < 4; ++k)
        WvT[(size_t)(tx * 32 + ly + 8 * k) * 1024 + ty * 32 + lx] = f2bf(t[lx][ly + 8 * k]);
    } else {
      int ti = blk - 3072;
      int tx = ti & 3, ty = ti >> 2;
#pragma unroll
      for (int k = 0; k < 4; ++k)
        t[ly + 8 * k][lx] = Wfc[(size_t)(ty * 32 + ly + 8 * k) * 128 + tx * 32 + lx];
      __syncthreads();
#pragma unroll
      for (int k = 0; k < 4; ++k) {
        float v = t[lx][ly + 8 * k];
        u16 h = f2bf(v);
        size_t o = (size_t)(tx * 32 + ly + 8 * k) * 1024 + ty * 32 + lx;
        WfcThi[o] = h;
        WfcTlo[o] = f2bf(v - bf2f(h));
      }
    }
  } else {
    int wave = tid >> 6, lane = tid & 63;
    int row = (blk - 3200) * 4 + wave;
    float s = 0.f;
    for (int i = lane; i < 1024; i += 64)
      s += Wk[(size_t)row * 1024 + i] * bq[i];
#pragma unroll
    for (int m = 1; m < 64; m <<= 1) s += __shfl_xor(s, m);
    if (lane == 0) ak[row] = s;
  }
}

__global__ __launch_bounds__(256) void convert4_split(
    const float* __restrict__ f1, const float* __restrict__ f2,
    const float* __restrict__ f3, const float* __restrict__ f4,
    u16* __restrict__ Zhi, u16* __restrict__ Zlo)
{
  int a = blockIdx.x >> 13;
  const float* f = (a == 0) ? f1 : (a == 1) ? f2 : (a == 2) ? f3 : f4;
  size_t off = (size_t)(blockIdx.x & 8191) * 2048 + threadIdx.x * 8;
  size_t o = (size_t)a * B_SZ * H_SZ + off;
  float4 v0 = *(const float4*)(f + off);
  float4 v1 = *(const float4*)(f + off + 4);
  float vv[8] = {v0.x, v0.y, v0.z, v0.w, v1.x, v1.y, v1.z, v1.w};
  u32 hp[4], lp[4];
#pragma unroll
  for (int j = 0; j < 4; ++j) {
    u16 ha = f2bf(vv[2 * j]), hb = f2bf(vv[2 * j + 1]);
    hp[j] = (u32)ha | ((u32)hb << 16);
    lp[j] = (u32)f2bf(vv[2 * j] - bf2f(ha)) | ((u32)f2bf(vv[2 * j + 1] - bf2f(hb)) << 16);
  }
  *(uint4*)(Zhi + o) = make_uint4(hp[0], hp[1], hp[2], hp[3]);
  *(uint4*)(Zlo + o) = make_uint4(lp[0], lp[1], lp[2], lp[3]);
}

// one wave per batch: softmax rows of 4x4 logits, col-sums w_s, g = sum_s w_s z_s
__global__ __launch_bounds__(256) void softmax_g(
    const float* __restrict__ logits, const u16* __restrict__ Zhi,
    u16* __restrict__ G)
{
  const size_t FBS = (size_t)B_SZ * H_SZ;
  int wave = threadIdx.x >> 6, lane = threadIdx.x & 63;
  size_t b = (size_t)blockIdx.x * 4 + wave;
  float l[16];
#pragma unroll
  for (int i = 0; i < 16; ++i) l[i] = logits[b * 16 + i];
  float w0 = 0, w1 = 0, w2 = 0, w3 = 0;
#pragma unroll
  for (int t = 0; t < 4; ++t) {
    float a0 = l[t * 4], a1 = l[t * 4 + 1], a2 = l[t * 4 + 2], a3 = l[t * 4 + 3];
    float mx = fmaxf(fmaxf(a0, a1), fmaxf(a2, a3));
    float e0 = __expf(a0 - mx), e1 = __expf(a1 - mx), e2 = __expf(a2 - mx), e3 = __expf(a3 - mx);
    float inv = 1.0f / (e0 + e1 + e2 + e3);
    w0 += e0 * inv; w1 += e1 * inv; w2 += e2 * inv; w3 += e3 * inv;
  }
#pragma unroll
  for (int ch = 0; ch < 2; ++ch) {
    size_t h0 = (size_t)lane * 8 + ch * 512;
    float g[8];
#pragma unroll
    for (int j = 0; j < 8; ++j) g[j] = 0.f;
#pragma unroll
    for (int s = 0; s < 4; ++s) {
      float ws = (s == 0) ? w0 : (s == 1) ? w1 : (s == 2) ? w2 : w3;
      uint4 zz = *(const uint4*)(Zhi + (size_t)s * FBS + b * H_SZ + h0);
      u32 zs[4] = {zz.x, zz.y, zz.z, zz.w};
#pragma unroll
      for (int j = 0; j < 4; ++j) {
        g[2 * j]     += ws * bf2f((u16)(zs[j] & 0xffffu));
        g[2 * j + 1] += ws * bf2f((u16)(zs[j] >> 16));
      }
    }
    *(uint4*)(G + b * H_SZ + h0) =
        make_uint4(pk2(g[0], g[1]), pk2(g[2], g[3]), pk2(g[4], g[5]), pk2(g[6], g[7]));
  }
}

// one wave per row: softmax over 128 fc logits
__global__ __launch_bounds__(256) void softmax_out(
    const float* __restrict__ L2, float* __restrict__ out)
{
  int wave = threadIdx.x >> 6, lane = threadIdx.x & 63;
  size_t row = (size_t)blockIdx.x * 4 + wave;
  float2 v = *(const float2*)(L2 + row * 128 + lane * 2);
  float mx = fmaxf(v.x, v.y);
#pragma unroll
  for (int m = 1; m < 64; m <<= 1) mx = fmaxf(mx, __shfl_xor(mx, m));
  float e0 = __expf(v.x - mx), e1 = __expf(v.y - mx);
  float s = e0 + e1;
#pragma unroll
  for (int m = 1; m < 64; m <<= 1) s += __shfl_xor(s, m);
  float inv = 1.0f / s;
  *(float2*)(out + row * 128 + lane * 2) = make_float2(e0 * inv, e1 * inv);
}

extern "C" void kernel_launch(void* const* d_in, const int* in_sizes, int n_in,
                              void* d_out, int out_size, void* d_ws, size_t ws_size,
                              hipStream_t stream)
{
  const float* f1  = (const float*)d_in[0];
  const float* f2  = (const float*)d_in[1];
  const float* f3  = (const float*)d_in[2];
  const float* f4  = (const float*)d_in[3];
  const float* Wq  = (const float*)d_in[4];
  const float* bq  = (const float*)d_in[5];
  const float* Wk  = (const float*)d_in[6];
  // d_in[7] = bk: logit contribution constant over softmax axis -> dropped.
  const float* Wv  = (const float*)d_in[8];
  const float* bv  = (const float*)d_in[9];
  const float* Wfc = (const float*)d_in[10];
  const float* bfc = (const float*)d_in[11];

  float* x_out = (float*)d_out;
  float* out2  = x_out + (size_t)B_SZ * H_SZ;

  const size_t BH = (size_t)B_SZ * H_SZ;   // one feature slot (elements)
  const size_t HH = (size_t)H_SZ * H_SZ;
  char* w = (char*)d_ws;
  u16* Zhi = (u16*)w;  w += 4 * BH * sizeof(u16);   // 128 MiB
  u16* Zlo = (u16*)w;  w += 4 * BH * sizeof(u16);   // 128 MiB
  u16* Wqhi = (u16*)w;  w += HH * 2;
  u16* Wqlo = (u16*)w;  w += HH * 2;
  u16* Wkhi = (u16*)w;  w += HH * 2;
  u16* Wklo = (u16*)w;  w += HH * 2;
  u16* AThi = (u16*)w;  w += HH * 2;   // AT[n,k] = sum_i Wk[n,i]Wq[k,i]
  u16* ATlo = (u16*)w;  w += HH * 2;
  u16* WvT  = (u16*)w;  w += HH * 2;   // WvT[n,k] = Wv[k,n]
  u16* WfcThi = (u16*)w;  w += (size_t)OUT_SZ * H_SZ * 2;
  u16* WfcTlo = (u16*)w;  w += (size_t)OUT_SZ * H_SZ * 2;
  float* ak     = (float*)w;  w += H_SZ * sizeof(float);
  float* logits = (float*)w;  w += (size_t)B_SZ * 16 * sizeof(float);
  float* fcl    = (float*)w;  w += (size_t)B_SZ * OUT_SZ * sizeof(float);
  // Zlo is dead after gemm<1>: reuse for G / Xhi / Xlo.
  u16* G   = Zlo;
  u16* Xhi = Zlo + BH;
  u16* Xlo = Zlo + 2 * BH;

  hipMemsetAsync(logits, 0, (size_t)B_SZ * 16 * sizeof(float), stream);
  prep_weights<<<3456, 256, 0, stream>>>(Wq, Wk, Wv, Wfc, bq,
      Wqhi, Wqlo, Wkhi, Wklo, WvT, WfcThi, WfcTlo, ak);
  convert4_split<<<32768, 256, 0, stream>>>(f1, f2, f3, f4, Zhi, Zlo);
  // AT = Wk @ Wq^T, split-bf16 accurate, hi/lo out
  gemm_nt<0, 1><<<dim3(8, 8), 256, 0, stream>>>(
      Wkhi, Wklo, Wqhi, Wqlo, 1024, 1024,
      nullptr, AThi, ATlo, nullptr, nullptr, nullptr, nullptr, nullptr);
  // R = Z @ AT^T (split), fused fp32 (R+ak)·z epilogue -> logits[b,t,s]
  gemm_nt<1, 1><<<dim3(8, 512), 256, 0, stream>>>(
      Zhi, Zlo, AThi, ATlo, 1024, 1024,
      logits, nullptr, nullptr, ak, f1, f2, f3, f4);
  softmax_g<<<4096, 256, 0, stream>>>(logits, Zhi, G);
  // x = G @ Wv + 4*bv  (fp32 -> d_out, bf16 hi/lo -> Xhi/Xlo)
  gemm_nt<2, 0><<<dim3(8, 128), 256, 0, stream>>>(
      G, nullptr, WvT, nullptr, 1024, 1024,
      x_out, Xhi, Xlo, bv, nullptr, nullptr, nullptr, nullptr);
  // fc logits = x @ Wfc + bfc (split)
  gemm_nt<3, 1><<<dim3(1, 128), 256, 0, stream>>>(
      Xhi, Xlo, WfcThi, WfcTlo, 128, 1024,
      fcl, nullptr, nullptr, bfc, nullptr, nullptr, nullptr, nullptr);
  softmax_out<<<4096, 256, 0, stream>>>(fcl, out2);
}

// Round 3
// 785.830 us; speedup vs baseline: 1.5883x; 1.5883x over previous
//
#include <hip/hip_runtime.h>
#include <hip/hip_bf16.h>
#include <stdint.h>

#define B_SZ 16384
#define H_SZ 1024
#define OUT_SZ 128

typedef __attribute__((ext_vector_type(4))) float f32x4;
typedef __attribute__((ext_vector_type(8))) _Float16 h16x8;
typedef unsigned short u16;
typedef unsigned int u32;

__device__ __forceinline__ u16 f2h(float f) {
  union { _Float16 h; u16 u; } v; v.h = (_Float16)f; return v.u;
}
__device__ __forceinline__ float h2f(u16 u) {
  union { u16 u; _Float16 h; } v; v.u = u; return (float)v.h;
}
__device__ __forceinline__ u32 pk2(float a, float b) {
  return (u32)f2h(a) | ((u32)f2h(b) << 16);
}

__device__ __forceinline__ void gl_lds16(const void* g, void* l) {
  __builtin_amdgcn_global_load_lds(
      (const __attribute__((address_space(1))) u32*)g,
      (__attribute__((address_space(3))) u32*)l, 16, 0, 0);
}

// ---------------------------------------------------------------------------
// NT GEMM: C[m,n] = sum_k A[m,k] * B[n,k], fp16 in, fp32 MFMA accum.
// BM=BN=128, BK=32, 256 threads (4 waves, 64x64 each via 4x4 mfma 16x16x32).
// Row tile = blockIdx.x (fastest; XCD round-robin spreads rows), col = .y.
// MODE 0: store fp16 C -> ep_b (AT prep)
// MODE 1: A = Z (4 stacked [B,H]; row m -> token m&3, batch m>>2);
//         epilogue: partial logits (R[t,n]+ak[n])*z_fp32[s,n] atomicAdd ep_f
// MODE 2: v = acc + 4*ep_v[n]; fp32 -> ep_f, fp16 -> ep_b
// MODE 3: ep_f[m*N+n] = acc + ep_v[n]   (fc logits)
// ---------------------------------------------------------------------------
template<int MODE>
__global__ __launch_bounds__(256, 4) void gemm_nt(
    const u16* __restrict__ Aptr, const u16* __restrict__ Bptr,
    int N, int K,
    float* __restrict__ ep_f, u16* __restrict__ ep_b,
    const float* __restrict__ ep_v,
    const float* zf0, const float* zf1, const float* zf2, const float* zf3)
{
  constexpr int BM = 128, BN = 128, BK = 32;
  __shared__ __align__(16) u16 sA[BM * BK];
  __shared__ __align__(16) u16 sB[BN * BK];
  const int tid  = threadIdx.x;
  const int wave = tid >> 6;
  const int lane = tid & 63;
  const int qd   = lane >> 4;
  const int c16  = lane & 15;
  const int bm0  = blockIdx.x * BM;
  const int bn0  = blockIdx.y * BN;
  const int wm   = (wave >> 1) * 64;
  const int wn   = (wave & 1) * 64;
  const size_t FBS = (size_t)B_SZ * H_SZ;

  f32x4 acc[4][4];
#pragma unroll
  for (int i = 0; i < 4; ++i)
#pragma unroll
    for (int j = 0; j < 4; ++j)
      acc[i][j] = (f32x4){0.f, 0.f, 0.f, 0.f};

  for (int k0 = 0; k0 < K; k0 += BK) {
    // ---- stage: 512 x 16B chunks per tile; LDS slot s holds global chunk
    // c = (s&3) ^ ((row>>1)&3) of row s>>2 (XOR swizzle keeps the
    // global_load_lds wave-contiguous while making frag reads <=2-way).
#pragma unroll
    for (int i = 0; i < 2; ++i) {
      int slot = tid + i * 256;
      int r = slot >> 2, pp = slot & 3;
      int cc = pp ^ ((r >> 1) & 3);
      {
        int gm = bm0 + r;
        const u16* gp;
        if (MODE == 1)
          gp = Aptr + (size_t)(gm & 3) * FBS + (size_t)(gm >> 2) * H_SZ + (k0 + cc * 8);
        else
          gp = Aptr + (size_t)gm * K + (k0 + cc * 8);
        gl_lds16(gp, &sA[(size_t)(slot & ~63) * 8]);
      }
      {
        int gn = bn0 + r;
        const u16* gp = Bptr + (size_t)gn * K + (k0 + cc * 8);
        gl_lds16(gp, &sB[(size_t)(slot & ~63) * 8]);
      }
    }
    __syncthreads();
    h16x8 af[4], bfr[4];
#pragma unroll
    for (int im = 0; im < 4; ++im) {
      int m = wm + im * 16 + c16;
      int slot = m * 4 + (qd ^ ((m >> 1) & 3));
      af[im] = *(const h16x8*)&sA[slot * 8];
    }
#pragma unroll
    for (int in = 0; in < 4; ++in) {
      int n = wn + in * 16 + c16;
      int slot = n * 4 + (qd ^ ((n >> 1) & 3));
      bfr[in] = *(const h16x8*)&sB[slot * 8];
    }
#pragma unroll
    for (int im = 0; im < 4; ++im)
#pragma unroll
      for (int in = 0; in < 4; ++in)
        acc[im][in] = __builtin_amdgcn_mfma_f32_16x16x32_f16(af[im], bfr[in], acc[im][in], 0, 0, 0);
    __syncthreads();
  }

  if constexpr (MODE == 0) {
#pragma unroll
    for (int im = 0; im < 4; ++im)
#pragma unroll
      for (int in = 0; in < 4; ++in) {
        int n = bn0 + wn + in * 16 + c16;
#pragma unroll
        for (int r = 0; r < 4; ++r) {
          int m = bm0 + wm + im * 16 + qd * 4 + r;
          ep_b[(size_t)m * N + n] = f2h(acc[im][in][r]);
        }
      }
  } else if constexpr (MODE == 1) {
    // acc row m = bm0+wm+im*16+qd*4+r -> batch b = m>>2, token t = r.
    // partial logit[b,t,s] over this block's 64 cols per wave:
    //   sum_n (R[t,n] + ak[n]) * z_fp32[s][b,n]
    const float* zf[4] = {zf0, zf1, zf2, zf3};
#pragma unroll
    for (int im = 0; im < 4; ++im) {
      int mrow = bm0 + wm + im * 16 + qd * 4;
      size_t b = (size_t)(mrow >> 2);
      float p[4][4];
#pragma unroll
      for (int r = 0; r < 4; ++r)
#pragma unroll
        for (int s = 0; s < 4; ++s) p[r][s] = 0.f;
#pragma unroll
      for (int in = 0; in < 4; ++in) {
        int n = bn0 + wn + in * 16 + c16;
        float akv = ep_v[n];
        float rv[4];
#pragma unroll
        for (int r = 0; r < 4; ++r) rv[r] = acc[im][in][r] + akv;
#pragma unroll
        for (int s = 0; s < 4; ++s) {
          float zv = zf[s][b * H_SZ + n];
#pragma unroll
          for (int r = 0; r < 4; ++r) p[r][s] += rv[r] * zv;
        }
      }
#pragma unroll
      for (int r = 0; r < 4; ++r)
#pragma unroll
        for (int s = 0; s < 4; ++s) {
          float v = p[r][s];
          v += __shfl_xor(v, 1);
          v += __shfl_xor(v, 2);
          v += __shfl_xor(v, 4);
          v += __shfl_xor(v, 8);
          if (c16 == 0) atomicAdd(&ep_f[b * 16 + r * 4 + s], v);
        }
    }
  } else if constexpr (MODE == 2) {
#pragma unroll
    for (int im = 0; im < 4; ++im)
#pragma unroll
      for (int in = 0; in < 4; ++in) {
        int n = bn0 + wn + in * 16 + c16;
        float bvv = 4.0f * ep_v[n];
#pragma unroll
        for (int r = 0; r < 4; ++r) {
          int m = bm0 + wm + im * 16 + qd * 4 + r;
          float v = acc[im][in][r] + bvv;
          ep_f[(size_t)m * H_SZ + n] = v;
          ep_b[(size_t)m * H_SZ + n] = f2h(v);
        }
      }
  } else {
#pragma unroll
    for (int im = 0; im < 4; ++im)
#pragma unroll
      for (int in = 0; in < 4; ++in) {
        int n = bn0 + wn + in * 16 + c16;
        float bc = ep_v[n];
#pragma unroll
        for (int r = 0; r < 4; ++r) {
          int m = bm0 + wm + im * 16 + qd * 4 + r;
          ep_f[(size_t)m * N + n] = acc[im][in][r] + bc;
        }
      }
  }
}

// ---------------------------------------------------------------------------
// prep_weights: [0,1024) Wq->fp16; [1024,2048) Wk->fp16;
// [2048,3072) WvT fp16 transpose; [3072,3200) WfcT fp16 transpose;
// [3200,3456) ak[h] = sum_i Wk[h,i]*bq[i]  (fp32)
// ---------------------------------------------------------------------------
__global__ __launch_bounds__(256) void prep_weights(
    const float* __restrict__ Wq, const float* __restrict__ Wk,
    const float* __restrict__ Wv, const float* __restrict__ Wfc,
    const float* __restrict__ bq,
    u16* __restrict__ Wq16, u16* __restrict__ Wk16,
    u16* __restrict__ WvT, u16* __restrict__ WfcT,
    float* __restrict__ ak)
{
  __shared__ float t[32][33];
  int blk = blockIdx.x, tid = threadIdx.x;
  if (blk < 2048) {
    const float* src = (blk < 1024) ? Wq : Wk;
    u16* dst = (blk < 1024) ? Wq16 : Wk16;
    size_t i0 = (size_t)(blk & 1023) * 1024 + tid * 4;
    float4 v = *(const float4*)(src + i0);
    *(uint2*)(dst + i0) = make_uint2(pk2(v.x, v.y), pk2(v.z, v.w));
  } else if (blk < 3200) {
    int lx = tid & 31, ly = tid >> 5;
    if (blk < 3072) {
      int ti = blk - 2048;
      int tx = ti & 31, ty = ti >> 5;
#pragma unroll
      for (int k = 0; k < 4; ++k)
        t[ly + 8 * k][lx] = Wv[(size_t)(ty * 32 + ly + 8 * k) * 1024 + tx * 32 + lx];
      __syncthreads();
#pragma unroll
      for (int k = 0; k < 4; ++k)
        WvT[(size_t)(tx * 32 + ly + 8 * k) * 1024 + ty * 32 + lx] = f2h(t[lx][ly + 8 * k]);
    } else {
      int ti = blk - 3072;
      int tx = ti & 3, ty = ti >> 2;
#pragma unroll
      for (int k = 0; k < 4; ++k)
        t[ly + 8 * k][lx] = Wfc[(size_t)(ty * 32 + ly + 8 * k) * 128 + tx * 32 + lx];
      __syncthreads();
#pragma unroll
      for (int k = 0; k < 4; ++k)
        WfcT[(size_t)(tx * 32 + ly + 8 * k) * 1024 + ty * 32 + lx] = f2h(t[lx][ly + 8 * k]);
    }
  } else {
    int wave = tid >> 6, lane = tid & 63;
    int row = (blk - 3200) * 4 + wave;
    float s = 0.f;
    for (int i = lane; i < 1024; i += 64)
      s += Wk[(size_t)row * 1024 + i] * bq[i];
#pragma unroll
    for (int m = 1; m < 64; m <<= 1) s += __shfl_xor(s, m);
    if (lane == 0) ak[row] = s;
  }
}

__global__ __launch_bounds__(256) void convert4(
    const float* __restrict__ f1, const float* __restrict__ f2,
    const float* __restrict__ f3, const float* __restrict__ f4,
    u16* __restrict__ Zh)
{
  int a = blockIdx.x >> 13;
  const float* f = (a == 0) ? f1 : (a == 1) ? f2 : (a == 2) ? f3 : f4;
  size_t off = (size_t)(blockIdx.x & 8191) * 2048 + threadIdx.x * 8;
  float4 v0 = *(const float4*)(f + off);
  float4 v1 = *(const float4*)(f + off + 4);
  *(uint4*)(Zh + (size_t)a * B_SZ * H_SZ + off) =
      make_uint4(pk2(v0.x, v0.y), pk2(v0.z, v0.w), pk2(v1.x, v1.y), pk2(v1.z, v1.w));
}

// one wave per batch: softmax rows of 4x4 logits, col-sums w_s, g = sum_s w_s z_s
__global__ __launch_bounds__(256) void softmax_g(
    const float* __restrict__ logits, const u16* __restrict__ Zh,
    u16* __restrict__ G)
{
  const size_t FBS = (size_t)B_SZ * H_SZ;
  int wave = threadIdx.x >> 6, lane = threadIdx.x & 63;
  size_t b = (size_t)blockIdx.x * 4 + wave;
  float l[16];
#pragma unroll
  for (int i = 0; i < 16; ++i) l[i] = logits[b * 16 + i];
  float w0 = 0, w1 = 0, w2 = 0, w3 = 0;
#pragma unroll
  for (int t = 0; t < 4; ++t) {
    float a0 = l[t * 4], a1 = l[t * 4 + 1], a2 = l[t * 4 + 2], a3 = l[t * 4 + 3];
    float mx = fmaxf(fmaxf(a0, a1), fmaxf(a2, a3));
    float e0 = __expf(a0 - mx), e1 = __expf(a1 - mx), e2 = __expf(a2 - mx), e3 = __expf(a3 - mx);
    float inv = 1.0f / (e0 + e1 + e2 + e3);
    w0 += e0 * inv; w1 += e1 * inv; w2 += e2 * inv; w3 += e3 * inv;
  }
#pragma unroll
  for (int ch = 0; ch < 2; ++ch) {
    size_t h0 = (size_t)lane * 8 + ch * 512;
    float g[8];
#pragma unroll
    for (int j = 0; j < 8; ++j) g[j] = 0.f;
#pragma unroll
    for (int s = 0; s < 4; ++s) {
      float ws = (s == 0) ? w0 : (s == 1) ? w1 : (s == 2) ? w2 : w3;
      uint4 zz = *(const uint4*)(Zh + (size_t)s * FBS + b * H_SZ + h0);
      u32 zs[4] = {zz.x, zz.y, zz.z, zz.w};
#pragma unroll
      for (int j = 0; j < 4; ++j) {
        g[2 * j]     += ws * h2f((u16)(zs[j] & 0xffffu));
        g[2 * j + 1] += ws * h2f((u16)(zs[j] >> 16));
      }
    }
    *(uint4*)(G + b * H_SZ + h0) =
        make_uint4(pk2(g[0], g[1]), pk2(g[2], g[3]), pk2(g[4], g[5]), pk2(g[6], g[7]));
  }
}

// one wave per row: softmax over 128 fc logits
__global__ __launch_bounds__(256) void softmax_out(
    const float* __restrict__ L2, float* __restrict__ out)
{
  int wave = threadIdx.x >> 6, lane = threadIdx.x & 63;
  size_t row = (size_t)blockIdx.x * 4 + wave;
  float2 v = *(const float2*)(L2 + row * 128 + lane * 2);
  float mx = fmaxf(v.x, v.y);
#pragma unroll
  for (int m = 1; m < 64; m <<= 1) mx = fmaxf(mx, __shfl_xor(mx, m));
  float e0 = __expf(v.x - mx), e1 = __expf(v.y - mx);
  float s = e0 + e1;
#pragma unroll
  for (int m = 1; m < 64; m <<= 1) s += __shfl_xor(s, m);
  float inv = 1.0f / s;
  *(float2*)(out + row * 128 + lane * 2) = make_float2(e0 * inv, e1 * inv);
}

extern "C" void kernel_launch(void* const* d_in, const int* in_sizes, int n_in,
                              void* d_out, int out_size, void* d_ws, size_t ws_size,
                              hipStream_t stream)
{
  const float* f1  = (const float*)d_in[0];
  const float* f2  = (const float*)d_in[1];
  const float* f3  = (const float*)d_in[2];
  const float* f4  = (const float*)d_in[3];
  const float* Wq  = (const float*)d_in[4];
  const float* bq  = (const float*)d_in[5];
  const float* Wk  = (const float*)d_in[6];
  // d_in[7] = bk: logit contribution constant over softmax axis -> dropped.
  const float* Wv  = (const float*)d_in[8];
  const float* bv  = (const float*)d_in[9];
  const float* Wfc = (const float*)d_in[10];
  const float* bfc = (const float*)d_in[11];

  float* x_out = (float*)d_out;
  float* out2  = x_out + (size_t)B_SZ * H_SZ;

  const size_t BH = (size_t)B_SZ * H_SZ;
  const size_t HH = (size_t)H_SZ * H_SZ;
  char* w = (char*)d_ws;
  u16* Zh   = (u16*)w;  w += 4 * BH * sizeof(u16);   // 128 MiB fp16 z
  u16* G    = (u16*)w;  w += BH * sizeof(u16);       // 32 MiB
  u16* Xh   = (u16*)w;  w += BH * sizeof(u16);       // 32 MiB
  u16* Wq16 = (u16*)w;  w += HH * 2;
  u16* Wk16 = (u16*)w;  w += HH * 2;
  u16* AT   = (u16*)w;  w += HH * 2;   // AT[i,h] = sum_j Wk[i,j]Wq[h,j]
  u16* WvT  = (u16*)w;  w += HH * 2;   // WvT[n,k] = Wv[k,n]
  u16* WfcT = (u16*)w;  w += (size_t)OUT_SZ * H_SZ * 2;
  float* ak     = (float*)w;  w += H_SZ * sizeof(float);
  float* logits = (float*)w;  w += (size_t)B_SZ * 16 * sizeof(float);
  float* fcl    = (float*)w;  w += (size_t)B_SZ * OUT_SZ * sizeof(float);

  hipMemsetAsync(logits, 0, (size_t)B_SZ * 16 * sizeof(float), stream);
  prep_weights<<<3456, 256, 0, stream>>>(Wq, Wk, Wv, Wfc, bq,
      Wq16, Wk16, WvT, WfcT, ak);
  convert4<<<32768, 256, 0, stream>>>(f1, f2, f3, f4, Zh);
  // AT = Wk @ Wq^T (fp16 out)
  gemm_nt<0><<<dim3(8, 8), 256, 0, stream>>>(
      Wk16, Wq16, 1024, 1024, nullptr, AT, nullptr,
      nullptr, nullptr, nullptr, nullptr);
  // R = Z @ AT^T, fused fp32 (R+ak)·z epilogue -> logits[b,t,s]
  gemm_nt<1><<<dim3(512, 8), 256, 0, stream>>>(
      Zh, AT, 1024, 1024, logits, nullptr, ak, f1, f2, f3, f4);
  softmax_g<<<4096, 256, 0, stream>>>(logits, Zh, G);
  // x = G @ Wv + 4*bv  (fp32 -> d_out, fp16 -> Xh)
  gemm_nt<2><<<dim3(128, 8), 256, 0, stream>>>(
      G, WvT, 1024, 1024, x_out, Xh, bv,
      nullptr, nullptr, nullptr, nullptr);
  // fc logits = x @ Wfc + bfc
  gemm_nt<3><<<dim3(128, 1), 256, 0, stream>>>(
      Xh, WfcT, 128, 1024, fcl, nullptr, bfc,
      nullptr, nullptr, nullptr, nullptr);
  softmax_out<<<4096, 256, 0, stream>>>(fcl, out2);
}